// Round 6
// baseline (185.279 us; speedup 1.0000x reference)
//
#include <hip/hip_runtime.h>
#include <hip/hip_bf16.h>

// Problem sizes (fixed)
#define BB   16
#define SS   32
#define TKK  128
#define NN   512
#define LPB  4096            // S*TK rows per batch
#define RPB  64              // rows per tile
#define TPB  4               // tiles per persistent block

using bf16x8 = __attribute__((ext_vector_type(8))) __bf16;
using f32x4  = __attribute__((ext_vector_type(4))) float;

__device__ inline unsigned pack_bf16(float a, float b) {
  unsigned ua = __float_as_uint(a);
  unsigned ub = __float_as_uint(b);
  ua = (ua + 0x7FFFu + ((ua >> 16) & 1u)) >> 16;   // RNE
  ub = (ub + 0x7FFFu + ((ub >> 16) & 1u)) >> 16;
  return ua | (ub << 16);
}

__device__ inline float tanh_fast(float x) {
  float e = __expf(2.0f * x);
  return 1.0f - 2.0f * __builtin_amdgcn_rcpf(e + 1.0f);
}

// Frag index for (row-tile rt, k-slice ks, lane): (rt*16+ks)*64 + lane,
// lane = lh*16 + lr; covers k = ks*32 + lh*4 + {0..3, 16..19}, row = rt*16+lr.
// swz() is an involution spreading LDS banks (stays within a 4096-frag tile).
__device__ inline int swz(int f) { return f ^ ((f >> 4) & 15); }

// ---------------------------------------------------------------------------
// Merged prep (512-thread blocks):
//  blocks [0,8):  repack W_h (fp32 [m][k]) -> bf16 B-frag order via LDS
//  blocks [8,24): dec_fea = s_t_hat @ W_d^T + b_d
// ---------------------------------------------------------------------------
__global__ __launch_bounds__(512)
void prep_kernel(const float* __restrict__ W_h, uint4* __restrict__ Wpack,
                 const float* __restrict__ s_t_hat,
                 const float* __restrict__ W_d,
                 const float* __restrict__ b_d,
                 float* __restrict__ decfea) {
  __shared__ __align__(16) uint4 Wf[4096];     // 64 KiB
  int tid = threadIdx.x;
  if (blockIdx.x < 8) {
    int tile = blockIdx.x;                     // 64 m-rows per tile
    const float4* wblk = reinterpret_cast<const float4*>(W_h + (size_t)tile * 64 * NN);
    #pragma unroll
    for (int i = 0; i < 8; ++i) {
      int u   = i * 512 + tid;                 // frag id in [0,4096)
      int row = u >> 6;                        // m within tile
      int ks  = (u >> 2) & 15;
      int lh  = u & 3;
      int fb  = row * 128 + ks * 8 + lh;       // float4 index
      float4 h0 = wblk[fb];
      float4 h1 = wblk[fb + 4];                // +16 floats
      int frag = ((row >> 4) * 16 + ks) * 64 + lh * 16 + (row & 15);
      uint4 o;
      o.x = pack_bf16(h0.x, h0.y); o.y = pack_bf16(h0.z, h0.w);
      o.z = pack_bf16(h1.x, h1.y); o.w = pack_bf16(h1.z, h1.w);
      Wf[swz(frag)] = o;
    }
    __syncthreads();
    #pragma unroll
    for (int i = 0; i < 8; ++i) {
      int f = i * 512 + tid;
      Wpack[tile * 4096 + f] = Wf[swz(f)];
    }
  } else {
    int idx = (blockIdx.x - 8) * 512 + tid;    // 8192 total
    int b = idx >> 9, m = idx & 511;
    const float4* sp = reinterpret_cast<const float4*>(s_t_hat + b * NN);
    const float4* wp = reinterpret_cast<const float4*>(W_d + m * NN);
    float acc = 0.f;
    #pragma unroll 8
    for (int i = 0; i < NN / 4; ++i) {
      float4 a = sp[i], w = wp[i];
      acc += a.x * w.x + a.y * w.y + a.z * w.z + a.w * w.w;
    }
    decfea[idx] = acc + b_d[m];
  }
}

// ---------------------------------------------------------------------------
// Persistent fused score kernel. 256 blocks x 512 threads (8 waves), 1/CU.
// Each block processes 4 consecutive 64-row tiles with double-buffered LDS:
// while MFMAing tile t, the float4 loads + bf16 pack + ds_write for tile t+1
// are interleaved into the ks loop (static indices only -> no scratch).
// Wave w owns m-tiles [w*4, w*4+4); B prefetch depth 2 (3-buffer rotation).
// launch_bounds(512,2) -> 256-reg cap: acc 64 + B 48 + stage 24 fits.
// ---------------------------------------------------------------------------
__global__ __launch_bounds__(512, 2)
void score_kernel(const float* __restrict__ h,
                  const float* __restrict__ coverage,
                  const float* __restrict__ beta,
                  const float* __restrict__ W_c,
                  const float* __restrict__ v,
                  const uint4* __restrict__ Wpack,
                  const float* __restrict__ decfea,
                  float* __restrict__ weighted) {
  __shared__ __align__(16) uint4 Abuf[2][4096];   // 128 KiB (2 x 64-row tile)
  __shared__ float scorebuf[8][RPB];              // 2 KiB
  int tid   = threadIdx.x;
  int lane  = tid & 63;
  int w     = tid >> 6;                 // wave id 0..7
  int col   = lane & 15;                // C/D col
  int rhi   = (lane >> 4) << 2;         // C/D row base
  int tile0 = blockIdx.x * TPB;         // 4 tiles per block, same batch
  int bidx  = tile0 >> 6;

  // hoisted per-wave epilogue operands
  float dv[4], wc[4], vv[4];
  #pragma unroll
  for (int q = 0; q < 4; ++q) {
    int m = (w * 4 + q) * 16 + col;
    dv[q] = decfea[bidx * NN + m];
    wc[q] = W_c[m];
    vv[q] = v[m];
  }

  const bf16x8* Bv = reinterpret_cast<const bf16x8*>(Wpack) + (size_t)(w * 4) * 16 * 64 + lane;

  // ---- full stage of tile0 into Abuf[0] ----
  {
    const float4* hb = reinterpret_cast<const float4*>(h + (size_t)tile0 * RPB * NN);
    #pragma unroll
    for (int p = 0; p < 8; ++p) {
      int u   = p * 512 + tid;
      int row = u >> 6, kss = (u >> 2) & 15, lh = u & 3;
      int fb  = row * 128 + kss * 8 + lh;
      float4 h0 = hb[fb], h1 = hb[fb + 4];
      int frag = ((row >> 4) * 16 + kss) * 64 + lh * 16 + (row & 15);
      uint4 o;
      o.x = pack_bf16(h0.x, h0.y); o.y = pack_bf16(h0.z, h0.w);
      o.z = pack_bf16(h1.x, h1.y); o.w = pack_bf16(h1.z, h1.w);
      Abuf[0][swz(frag)] = o;
    }
  }

  #pragma unroll
  for (int t = 0; t < TPB; ++t) {
    __syncthreads();                    // stage(t) complete, buf[(t+1)&1] free
    const uint4* curA = Abuf[t & 1];
    uint4*       nxtA = Abuf[(t + 1) & 1];
    const float4* hnx = reinterpret_cast<const float4*>(h + (size_t)(tile0 + t + 1) * RPB * NN);
    const bool HAS = (t < TPB - 1);

    f32x4 acc[4][4];
    const f32x4 zz = {0.f, 0.f, 0.f, 0.f};
    #pragma unroll
    for (int q = 0; q < 4; ++q)
      #pragma unroll
      for (int rt = 0; rt < 4; ++rt) acc[q][rt] = zz;

    bf16x8 bb[3][4];
    #pragma unroll
    for (int q = 0; q < 4; ++q) bb[0][q] = Bv[(q * 16 + 0) * 64];
    #pragma unroll
    for (int q = 0; q < 4; ++q) bb[1][q] = Bv[(q * 16 + 1) * 64];

    float4 sg[3][2];                    // stage pipeline: 3 pair-buffers

    #pragma unroll
    for (int ks = 0; ks < 16; ++ks) {
      // ---- interleaved stage of tile t+1: issue pair p on even ks, write p-2 ----
      if (HAS && (ks & 1) == 0) {
        const int p = ks >> 1;
        if (p >= 2) {
          const int pp = p - 2;
          int u = pp * 512 + tid;
          int row = u >> 6, kss = (u >> 2) & 15, lh = u & 3;
          int frag = ((row >> 4) * 16 + kss) * 64 + lh * 16 + (row & 15);
          float4 h0 = sg[pp % 3][0], h1 = sg[pp % 3][1];
          uint4 o;
          o.x = pack_bf16(h0.x, h0.y); o.y = pack_bf16(h0.z, h0.w);
          o.z = pack_bf16(h1.x, h1.y); o.w = pack_bf16(h1.z, h1.w);
          nxtA[swz(frag)] = o;
        }
        {
          int u = p * 512 + tid;
          int row = u >> 6, kss = (u >> 2) & 15, lh = u & 3;
          int fb = row * 128 + kss * 8 + lh;
          sg[p % 3][0] = hnx[fb];
          sg[p % 3][1] = hnx[fb + 4];
        }
      }
      // ---- B prefetch (depth 2) ----
      if (ks + 2 < 16) {
        #pragma unroll
        for (int q = 0; q < 4; ++q)
          bb[(ks + 2) % 3][q] = Bv[(q * 16 + ks + 2) * 64];
      }
      // ---- A fragments ----
      bf16x8 af[4];
      #pragma unroll
      for (int rt = 0; rt < 4; ++rt)
        af[rt] = *reinterpret_cast<const bf16x8*>(&curA[swz((rt * 16 + ks) * 64 + lane)]);
      // ---- MFMA ----
      #pragma unroll
      for (int q = 0; q < 4; ++q)
        #pragma unroll
        for (int rt = 0; rt < 4; ++rt)
          acc[q][rt] = __builtin_amdgcn_mfma_f32_16x16x32_bf16(af[rt], bb[ks % 3][q], acc[q][rt], 0, 0, 0);
    }
    // ---- stage tail: write pairs 6,7 ----
    if (HAS) {
      #pragma unroll
      for (int pp = 6; pp < 8; ++pp) {
        int u = pp * 512 + tid;
        int row = u >> 6, kss = (u >> 2) & 15, lh = u & 3;
        int frag = ((row >> 4) * 16 + kss) * 64 + lh * 16 + (row & 15);
        float4 h0 = sg[pp % 3][0], h1 = sg[pp % 3][1];
        uint4 o;
        o.x = pack_bf16(h0.x, h0.y); o.y = pack_bf16(h0.z, h0.w);
        o.z = pack_bf16(h1.x, h1.y); o.w = pack_bf16(h1.z, h1.w);
        nxtA[swz(frag)] = o;
      }
    }

    // ---- epilogue: + dec_fea + cov*W_c, tanh, v-weighted reduce over m ----
    float cvl[4][4];
    #pragma unroll
    for (int rt = 0; rt < 4; ++rt)
      #pragma unroll
      for (int r = 0; r < 4; ++r)
        cvl[rt][r] = coverage[(tile0 + t) * RPB + rt * 16 + rhi + r];

    float sc[4][4] = {};
    #pragma unroll
    for (int q = 0; q < 4; ++q)
      #pragma unroll
      for (int rt = 0; rt < 4; ++rt)
        #pragma unroll
        for (int r = 0; r < 4; ++r) {
          float x = acc[q][rt][r] + dv[q] + cvl[rt][r] * wc[q];
          sc[rt][r] += vv[q] * tanh_fast(x);
        }
    #pragma unroll
    for (int rt = 0; rt < 4; ++rt)
      #pragma unroll
      for (int r = 0; r < 4; ++r) {
        float s = sc[rt][r];
        s += __shfl_xor(s, 1);
        s += __shfl_xor(s, 2);
        s += __shfl_xor(s, 4);
        s += __shfl_xor(s, 8);
        sc[rt][r] = s;
      }
    if (col == 0) {
      #pragma unroll
      for (int rt = 0; rt < 4; ++rt)
        #pragma unroll
        for (int r = 0; r < 4; ++r)
          scorebuf[w][rt * 16 + rhi + r] = sc[rt][r];
    }
    __syncthreads();
    if (tid < RPB) {
      float total = 0.f;
      #pragma unroll
      for (int ww = 0; ww < 8; ++ww) total += scorebuf[ww][tid];
      int gl = (tile0 + t) * RPB + tid;
      int lb = gl & (LPB - 1);
      int s  = lb >> 7;                 // TK = 128
      weighted[bidx * LPB + lb] = beta[bidx * SS + s] * total;
    }
  }
}

// ---------------------------------------------------------------------------
// Softmax over 4096 per batch, mask, renormalize; write attn_dist + coverage_new.
// Also zeroes c_t for the following atomic-accumulate kernel.
// ---------------------------------------------------------------------------
__global__ void softmax_kernel(const float* __restrict__ coverage,
                               const float* __restrict__ mask,
                               float* __restrict__ out) {
  int b = blockIdx.x;
  int t = threadIdx.x;
  float* ct   = out;                     // [0, 8192)
  float* attn = out + 8192;              // weighted in, attn_dist out
  float* covn = out + 8192 + 65536;      // coverage_new

  ct[b * NN + t] = 0.f;
  ct[b * NN + 256 + t] = 0.f;

  float wv[16];
  float mx = -1e30f;
  #pragma unroll
  for (int i = 0; i < 16; ++i) {
    wv[i] = attn[b * LPB + i * 256 + t];
    mx = fmaxf(mx, wv[i]);
  }
  __shared__ float redm[4], reds[4];
  mx = fmaxf(mx, __shfl_xor(mx, 1));
  mx = fmaxf(mx, __shfl_xor(mx, 2));
  mx = fmaxf(mx, __shfl_xor(mx, 4));
  mx = fmaxf(mx, __shfl_xor(mx, 8));
  mx = fmaxf(mx, __shfl_xor(mx, 16));
  mx = fmaxf(mx, __shfl_xor(mx, 32));
  if ((t & 63) == 0) redm[t >> 6] = mx;
  __syncthreads();
  mx = fmaxf(fmaxf(redm[0], redm[1]), fmaxf(redm[2], redm[3]));

  float e[16];
  float sum = 0.f;
  #pragma unroll
  for (int i = 0; i < 16; ++i) {
    e[i] = __expf(wv[i] - mx) * mask[b * LPB + i * 256 + t];
    sum += e[i];
  }
  sum += __shfl_xor(sum, 1);
  sum += __shfl_xor(sum, 2);
  sum += __shfl_xor(sum, 4);
  sum += __shfl_xor(sum, 8);
  sum += __shfl_xor(sum, 16);
  sum += __shfl_xor(sum, 32);
  if ((t & 63) == 0) reds[t >> 6] = sum;
  __syncthreads();
  sum = reds[0] + reds[1] + reds[2] + reds[3];
  float inv = 1.0f / sum;
  #pragma unroll
  for (int i = 0; i < 16; ++i) {
    int l = i * 256 + t;
    float a = e[i] * inv;
    attn[b * LPB + l] = a;
    covn[b * LPB + l] = coverage[b * LPB + l] + a;
  }
}

// ---------------------------------------------------------------------------
// c_t[b][n] = sum_l attn[b][l] * h[b][l][n]  (memory-bound, atomic partials)
// R3-proven version: float2 loads, one atomic per distinct address.
// ---------------------------------------------------------------------------
__global__ void ct_kernel(const float* __restrict__ h, float* __restrict__ out) {
  int blk   = blockIdx.x;                // 1024
  int b     = blk >> 6;
  int chunk = blk & 63;
  int t     = threadIdx.x;
  const float* attn = out + 8192 + b * LPB + chunk * 64;
  __shared__ float as_[64];
  if (t < 64) as_[t] = attn[t];
  __syncthreads();
  const float* hp = h + (size_t)(b * LPB + chunk * 64) * NN;
  float a0 = 0.f, a1 = 0.f;
  #pragma unroll 4
  for (int r = 0; r < 64; ++r) {
    float2 hv = *reinterpret_cast<const float2*>(hp + r * NN + t * 2);
    float av = as_[r];
    a0 += av * hv.x;
    a1 += av * hv.y;
  }
  atomicAdd(&out[b * NN + t * 2],     a0);
  atomicAdd(&out[b * NN + t * 2 + 1], a1);
}

extern "C" void kernel_launch(void* const* d_in, const int* in_sizes, int n_in,
                              void* d_out, int out_size, void* d_ws, size_t ws_size,
                              hipStream_t stream) {
  const float* s_t_hat  = (const float*)d_in[0];
  const float* h        = (const float*)d_in[1];
  const float* coverage = (const float*)d_in[2];
  const float* mask     = (const float*)d_in[3];
  const float* beta     = (const float*)d_in[4];
  const float* W_h      = (const float*)d_in[5];
  const float* W_c      = (const float*)d_in[6];
  const float* W_d      = (const float*)d_in[7];
  const float* b_d      = (const float*)d_in[8];
  const float* v        = (const float*)d_in[9];
  float* out = (float*)d_out;

  uint4* Wpack    = (uint4*)d_ws;           // 512 KiB
  float* decfea   = out + 8192 + 65536;     // staged in coverage_new region
  float* weighted = out + 8192;             // staged in attn_dist region

  prep_kernel <<<24, 512, 0, stream>>>(W_h, Wpack, s_t_hat, W_d, b_d, decfea);
  score_kernel<<<256, 512, 0, stream>>>(h, coverage, beta, W_c, v, Wpack, decfea, weighted);
  softmax_kernel<<<16, 256, 0, stream>>>(coverage, mask, out);
  ct_kernel<<<1024, 256, 0, stream>>>(h, out);
}

// Round 7
// 165.428 us; speedup vs baseline: 1.1200x; 1.1200x over previous
//
#include <hip/hip_runtime.h>
#include <hip/hip_bf16.h>

// Problem sizes (fixed)
#define BB   16
#define SS   32
#define TKK  128
#define NN   512
#define LPB  4096            // S*TK rows per batch
#define RPB  64              // rows per tile
#define NTILES 1024          // B*S*TK/RPB

using bf16x8 = __attribute__((ext_vector_type(8))) __bf16;
using f32x4  = __attribute__((ext_vector_type(4))) float;

__device__ inline unsigned pack_bf16(float a, float b) {
  unsigned ua = __float_as_uint(a);
  unsigned ub = __float_as_uint(b);
  ua = (ua + 0x7FFFu + ((ua >> 16) & 1u)) >> 16;   // RNE
  ub = (ub + 0x7FFFu + ((ub >> 16) & 1u)) >> 16;
  return ua | (ub << 16);
}

__device__ inline float tanh_fast(float x) {
  float e = __expf(2.0f * x);
  return 1.0f - 2.0f * __builtin_amdgcn_rcpf(e + 1.0f);
}

// Frag index for (row-tile rt, k-slice ks, lane): (rt*16+ks)*64 + lane,
// lane = lh*16 + lr; covers k = ks*32 + lh*4 + {0..3, 16..19}, row = rt*16+lr.
// swz() is an involution used ONLY inside the convert kernels' LDS bounce.
__device__ inline int swz(int f) { return f ^ ((f >> 4) & 15); }

// ---------------------------------------------------------------------------
// prep_convert (512-thread blocks):
//  blocks [0,1024):      convert h 64-row tile -> bf16 frag-order hpack
//                        (coalesced read, LDS bounce, coalesced write)
//  blocks [1024,1032):   repack W_h -> bf16 B-frag order Wpack
//  blocks [1032,1048):   dec_fea = s_t_hat @ W_d^T + b_d
// Pure streaming: no inter-phase barriers against compute.
// ---------------------------------------------------------------------------
__global__ __launch_bounds__(512)
void prep_convert(const float* __restrict__ h, uint4* __restrict__ hpack,
                  const float* __restrict__ W_h, uint4* __restrict__ Wpack,
                  const float* __restrict__ s_t_hat,
                  const float* __restrict__ W_d,
                  const float* __restrict__ b_d,
                  float* __restrict__ decfea) {
  __shared__ __align__(16) uint4 Wf[4096];     // 64 KiB
  int tid = threadIdx.x;
  int bid = blockIdx.x;
  if (bid < NTILES) {
    const float4* hb = reinterpret_cast<const float4*>(h + (size_t)bid * RPB * NN);
    #pragma unroll
    for (int i = 0; i < 8; ++i) {
      int u   = i * 512 + tid;                 // frag id in [0,4096)
      int row = u >> 6, kss = (u >> 2) & 15, lh = u & 3;
      int fb  = row * 128 + kss * 8 + lh;      // float4 index
      float4 h0 = hb[fb];
      float4 h1 = hb[fb + 4];                  // +16 floats
      int frag = ((row >> 4) * 16 + kss) * 64 + lh * 16 + (row & 15);
      uint4 o;
      o.x = pack_bf16(h0.x, h0.y); o.y = pack_bf16(h0.z, h0.w);
      o.z = pack_bf16(h1.x, h1.y); o.w = pack_bf16(h1.z, h1.w);
      Wf[swz(frag)] = o;
    }
    __syncthreads();
    uint4* dst = hpack + (size_t)bid * 4096;
    #pragma unroll
    for (int i = 0; i < 8; ++i) {
      int f = i * 512 + tid;
      dst[f] = Wf[swz(f)];
    }
  } else if (bid < NTILES + 8) {
    int tile = bid - NTILES;                   // 64 m-rows per tile
    const float4* wblk = reinterpret_cast<const float4*>(W_h + (size_t)tile * 64 * NN);
    #pragma unroll
    for (int i = 0; i < 8; ++i) {
      int u   = i * 512 + tid;
      int row = u >> 6, kss = (u >> 2) & 15, lh = u & 3;
      int fb  = row * 128 + kss * 8 + lh;
      float4 h0 = wblk[fb];
      float4 h1 = wblk[fb + 4];
      int frag = ((row >> 4) * 16 + kss) * 64 + lh * 16 + (row & 15);
      uint4 o;
      o.x = pack_bf16(h0.x, h0.y); o.y = pack_bf16(h0.z, h0.w);
      o.z = pack_bf16(h1.x, h1.y); o.w = pack_bf16(h1.z, h1.w);
      Wf[swz(frag)] = o;
    }
    __syncthreads();
    #pragma unroll
    for (int i = 0; i < 8; ++i) {
      int f = i * 512 + tid;
      Wpack[tile * 4096 + f] = Wf[swz(f)];
    }
  } else {
    int idx = (bid - NTILES - 8) * 512 + tid;  // 8192 total
    int b = idx >> 9, m = idx & 511;
    const float4* sp = reinterpret_cast<const float4*>(s_t_hat + b * NN);
    const float4* wp = reinterpret_cast<const float4*>(W_d + m * NN);
    float acc = 0.f;
    #pragma unroll 8
    for (int i = 0; i < NN / 4; ++i) {
      float4 a = sp[i], w = wp[i];
      acc += a.x * w.x + a.y * w.y + a.z * w.z + a.w * w.w;
    }
    decfea[idx] = acc + b_d[m];
  }
}

// ---------------------------------------------------------------------------
// Lean score kernel. 1024 blocks x 512 threads (8 waves); wave w owns m-tiles
// [w*4, w*4+4). Stage = 64 KiB linear async DMA (global_load_lds width 16)
// from the pre-packed bf16 hpack (L3-hot). Inner loop: 4 ds_read_b128 +
// 4 coalesced B loads (L2-hot) + 16 MFMA per ks step (R3-proven structure).
// ---------------------------------------------------------------------------
__global__ __launch_bounds__(512, 4)
void score_kernel(const uint4* __restrict__ hpack,
                  const float* __restrict__ coverage,
                  const float* __restrict__ beta,
                  const float* __restrict__ W_c,
                  const float* __restrict__ v,
                  const uint4* __restrict__ Wpack,
                  const float* __restrict__ decfea,
                  float* __restrict__ weighted) {
  __shared__ __align__(16) uint4 Abuf[4096];      // 64 KiB, linear frag order
  __shared__ float scorebuf[8][RPB];              // 2 KiB
  int tid  = threadIdx.x;
  int lane = tid & 63;
  int w    = tid >> 6;                  // wave id 0..7
  int col  = lane & 15;                 // C/D col
  int rhi  = (lane >> 4) << 2;          // C/D row base
  int rb   = blockIdx.x;
  int bidx = rb >> 6;

  // ---- async stage: 8 x global_load_lds (16B/lane), linear dest ----
  const uint4* hsrc = hpack + (size_t)rb * 4096;
  #pragma unroll
  for (int i = 0; i < 8; ++i) {
    int f     = i * 512 + tid;
    int fbase = i * 512 + (tid & ~63);  // wave-uniform LDS base
    __builtin_amdgcn_global_load_lds(
        (const __attribute__((address_space(1))) void*)(hsrc + f),
        (__attribute__((address_space(3))) void*)(&Abuf[fbase]),
        16, 0, 0);
  }

  // ---- hoist epilogue operands (independent of LDS) ----
  float cvl[4][4];
  #pragma unroll
  for (int rt = 0; rt < 4; ++rt)
    #pragma unroll
    for (int r = 0; r < 4; ++r)
      cvl[rt][r] = coverage[rb * RPB + rt * 16 + rhi + r];
  float dv[4], wc[4], vv[4];
  #pragma unroll
  for (int q = 0; q < 4; ++q) {
    int m = (w * 4 + q) * 16 + col;
    dv[q] = decfea[bidx * NN + m];
    wc[q] = W_c[m];
    vv[q] = v[m];
  }

  __syncthreads();                      // drains the LDS-DMA (vmcnt 0)

  f32x4 acc[4][4];
  const f32x4 zz = {0.f, 0.f, 0.f, 0.f};
  #pragma unroll
  for (int q = 0; q < 4; ++q)
    #pragma unroll
    for (int rt = 0; rt < 4; ++rt) acc[q][rt] = zz;

  const bf16x8* Afv = reinterpret_cast<const bf16x8*>(Abuf);
  const bf16x8* Bv  = reinterpret_cast<const bf16x8*>(Wpack) + (size_t)(w * 4) * 16 * 64 + lane;

  // software-prefetched B: load ks+1 frags while MFMAing ks (depth 1)
  bf16x8 bf[4];
  #pragma unroll
  for (int q = 0; q < 4; ++q)
    bf[q] = Bv[(q * 16 + 0) * 64];
  for (int ks = 0; ks < 16; ++ks) {
    bf16x8 af[4];
    #pragma unroll
    for (int rt = 0; rt < 4; ++rt)
      af[rt] = Afv[(rt * 16 + ks) * 64 + lane];
    bf16x8 bn[4];
    if (ks < 15) {
      #pragma unroll
      for (int q = 0; q < 4; ++q)
        bn[q] = Bv[(q * 16 + ks + 1) * 64];
    }
    #pragma unroll
    for (int q = 0; q < 4; ++q)
      #pragma unroll
      for (int rt = 0; rt < 4; ++rt)
        acc[q][rt] = __builtin_amdgcn_mfma_f32_16x16x32_bf16(af[rt], bf[q], acc[q][rt], 0, 0, 0);
    if (ks < 15) {
      #pragma unroll
      for (int q = 0; q < 4; ++q) bf[q] = bn[q];
    }
  }

  // ---- epilogue: + dec_fea + cov*W_c, tanh, v-weighted reduce over m ----
  float sc[4][4] = {};
  #pragma unroll
  for (int q = 0; q < 4; ++q)
    #pragma unroll
    for (int rt = 0; rt < 4; ++rt)
      #pragma unroll
      for (int r = 0; r < 4; ++r) {
        float x = acc[q][rt][r] + dv[q] + cvl[rt][r] * wc[q];
        sc[rt][r] += vv[q] * tanh_fast(x);
      }
  #pragma unroll
  for (int rt = 0; rt < 4; ++rt)
    #pragma unroll
    for (int r = 0; r < 4; ++r) {
      float s = sc[rt][r];
      s += __shfl_xor(s, 1);
      s += __shfl_xor(s, 2);
      s += __shfl_xor(s, 4);
      s += __shfl_xor(s, 8);
      sc[rt][r] = s;
    }

  if (col == 0) {
    #pragma unroll
    for (int rt = 0; rt < 4; ++rt)
      #pragma unroll
      for (int r = 0; r < 4; ++r)
        scorebuf[w][rt * 16 + rhi + r] = sc[rt][r];
  }
  __syncthreads();
  if (tid < RPB) {
    float total = 0.f;
    #pragma unroll
    for (int ww = 0; ww < 8; ++ww) total += scorebuf[ww][tid];
    int gl = rb * RPB + tid;
    int lb = gl & (LPB - 1);
    int s  = lb >> 7;                   // TK = 128
    weighted[bidx * LPB + lb] = beta[bidx * SS + s] * total;
  }
}

// ---------------------------------------------------------------------------
// Softmax over 4096 per batch, mask, renormalize; write attn_dist + coverage_new.
// Also zeroes c_t for the following atomic-accumulate kernel.
// ---------------------------------------------------------------------------
__global__ void softmax_kernel(const float* __restrict__ coverage,
                               const float* __restrict__ mask,
                               float* __restrict__ out) {
  int b = blockIdx.x;
  int t = threadIdx.x;
  float* ct   = out;                     // [0, 8192)
  float* attn = out + 8192;              // weighted in, attn_dist out
  float* covn = out + 8192 + 65536;      // coverage_new

  ct[b * NN + t] = 0.f;
  ct[b * NN + 256 + t] = 0.f;

  float wv[16];
  float mx = -1e30f;
  #pragma unroll
  for (int i = 0; i < 16; ++i) {
    wv[i] = attn[b * LPB + i * 256 + t];
    mx = fmaxf(mx, wv[i]);
  }
  __shared__ float redm[4], reds[4];
  mx = fmaxf(mx, __shfl_xor(mx, 1));
  mx = fmaxf(mx, __shfl_xor(mx, 2));
  mx = fmaxf(mx, __shfl_xor(mx, 4));
  mx = fmaxf(mx, __shfl_xor(mx, 8));
  mx = fmaxf(mx, __shfl_xor(mx, 16));
  mx = fmaxf(mx, __shfl_xor(mx, 32));
  if ((t & 63) == 0) redm[t >> 6] = mx;
  __syncthreads();
  mx = fmaxf(fmaxf(redm[0], redm[1]), fmaxf(redm[2], redm[3]));

  float e[16];
  float sum = 0.f;
  #pragma unroll
  for (int i = 0; i < 16; ++i) {
    e[i] = __expf(wv[i] - mx) * mask[b * LPB + i * 256 + t];
    sum += e[i];
  }
  sum += __shfl_xor(sum, 1);
  sum += __shfl_xor(sum, 2);
  sum += __shfl_xor(sum, 4);
  sum += __shfl_xor(sum, 8);
  sum += __shfl_xor(sum, 16);
  sum += __shfl_xor(sum, 32);
  if ((t & 63) == 0) reds[t >> 6] = sum;
  __syncthreads();
  sum = reds[0] + reds[1] + reds[2] + reds[3];
  float inv = 1.0f / sum;
  #pragma unroll
  for (int i = 0; i < 16; ++i) {
    int l = i * 256 + t;
    float a = e[i] * inv;
    attn[b * LPB + l] = a;
    covn[b * LPB + l] = coverage[b * LPB + l] + a;
  }
}

// ---------------------------------------------------------------------------
// c_t[b][n] = sum_l attn[b][l] * h[b][l][n]  (memory-bound, atomic partials)
// R3-proven version: float2 loads, one atomic per distinct address.
// ---------------------------------------------------------------------------
__global__ void ct_kernel(const float* __restrict__ h, float* __restrict__ out) {
  int blk   = blockIdx.x;                // 1024
  int b     = blk >> 6;
  int chunk = blk & 63;
  int t     = threadIdx.x;
  const float* attn = out + 8192 + b * LPB + chunk * 64;
  __shared__ float as_[64];
  if (t < 64) as_[t] = attn[t];
  __syncthreads();
  const float* hp = h + (size_t)(b * LPB + chunk * 64) * NN;
  float a0 = 0.f, a1 = 0.f;
  #pragma unroll 4
  for (int r = 0; r < 64; ++r) {
    float2 hv = *reinterpret_cast<const float2*>(hp + r * NN + t * 2);
    float av = as_[r];
    a0 += av * hv.x;
    a1 += av * hv.y;
  }
  atomicAdd(&out[b * NN + t * 2],     a0);
  atomicAdd(&out[b * NN + t * 2 + 1], a1);
}

extern "C" void kernel_launch(void* const* d_in, const int* in_sizes, int n_in,
                              void* d_out, int out_size, void* d_ws, size_t ws_size,
                              hipStream_t stream) {
  const float* s_t_hat  = (const float*)d_in[0];
  const float* h        = (const float*)d_in[1];
  const float* coverage = (const float*)d_in[2];
  const float* mask     = (const float*)d_in[3];
  const float* beta     = (const float*)d_in[4];
  const float* W_h      = (const float*)d_in[5];
  const float* W_c      = (const float*)d_in[6];
  const float* W_d      = (const float*)d_in[7];
  const float* b_d      = (const float*)d_in[8];
  const float* v        = (const float*)d_in[9];
  float* out = (float*)d_out;

  uint4* Wpack    = (uint4*)d_ws;               // 512 KiB
  uint4* hpack    = (uint4*)d_ws + 32768;       // 64 MiB bf16 frag-order h
  float* decfea   = out + 8192 + 65536;         // staged in coverage_new region
  float* weighted = out + 8192;                 // staged in attn_dist region

  prep_convert<<<NTILES + 24, 512, 0, stream>>>(h, hpack, W_h, Wpack,
                                                s_t_hat, W_d, b_d, decfea);
  score_kernel<<<NTILES, 512, 0, stream>>>(hpack, coverage, beta, W_c, v,
                                           Wpack, decfea, weighted);
  softmax_kernel<<<16, 256, 0, stream>>>(coverage, mask, out);
  ct_kernel<<<1024, 256, 0, stream>>>(h, out);
}

// Round 8
// 132.124 us; speedup vs baseline: 1.4023x; 1.2521x over previous
//
#include <hip/hip_runtime.h>
#include <hip/hip_bf16.h>

// Problem sizes (fixed)
#define BB   16
#define SS   32
#define TKK  128
#define NN   512
#define LPB  4096            // S*TK rows per batch
#define RPB  32              // rows per score tile
#define NTILES 2048          // 65536 rows / RPB

using bf16x8 = __attribute__((ext_vector_type(8))) __bf16;
using f32x4  = __attribute__((ext_vector_type(4))) float;

__device__ inline unsigned pack_bf16(float a, float b) {
  unsigned ua = __float_as_uint(a);
  unsigned ub = __float_as_uint(b);
  ua = (ua + 0x7FFFu + ((ua >> 16) & 1u)) >> 16;   // RNE
  ub = (ub + 0x7FFFu + ((ub >> 16) & 1u)) >> 16;
  return ua | (ub << 16);
}

__device__ inline float tanh_fast(float x) {
  float e = __expf(2.0f * x);
  return 1.0f - 2.0f * __builtin_amdgcn_rcpf(e + 1.0f);
}

__device__ inline bf16x8 cvt8(f32x4 lo, f32x4 hi) {
  bf16x8 r;
  r[0] = (__bf16)lo[0]; r[1] = (__bf16)lo[1]; r[2] = (__bf16)lo[2]; r[3] = (__bf16)lo[3];
  r[4] = (__bf16)hi[0]; r[5] = (__bf16)hi[1]; r[6] = (__bf16)hi[2]; r[7] = (__bf16)hi[3];
  return r;
}

// ---------------------------------------------------------------------------
// Fragment convention (k-permuted, consistent across A and B):
// element e of lane (lh = lane>>4) holds source k = ks*32 + lh*8 + e.
// => A-frag = 32 contiguous bytes of the fp32 source row (two 16B granules).
// ---------------------------------------------------------------------------

// ---------------------------------------------------------------------------
// prep: blocks [0,64): Wpack frag f = 16B of bf16, direct gather (k-contig);
//       blocks [64,80): dec_fea = s_t_hat @ W_d^T + b_d.
// ---------------------------------------------------------------------------
__global__ __launch_bounds__(512)
void prep_kernel(const float* __restrict__ W_h, uint4* __restrict__ Wpack,
                 const float* __restrict__ s_t_hat,
                 const float* __restrict__ W_d,
                 const float* __restrict__ b_d,
                 float* __restrict__ decfea) {
  int tid = threadIdx.x;
  if (blockIdx.x < 64) {
    int f    = blockIdx.x * 512 + tid;         // 32768 frags
    int lane = f & 63;
    int ks   = (f >> 6) & 15;
    int mt   = f >> 10;
    int m    = mt * 16 + (lane & 15);
    int lh   = lane >> 4;
    const float4* wp = reinterpret_cast<const float4*>(W_h);
    float4 a = wp[m * 128 + ks * 8 + lh * 2];
    float4 b = wp[m * 128 + ks * 8 + lh * 2 + 1];
    uint4 o;
    o.x = pack_bf16(a.x, a.y); o.y = pack_bf16(a.z, a.w);
    o.z = pack_bf16(b.x, b.y); o.w = pack_bf16(b.z, b.w);
    Wpack[f] = o;
  } else {
    int idx = (blockIdx.x - 64) * 512 + tid;   // 8192 total
    int b = idx >> 9, m = idx & 511;
    const float4* sp = reinterpret_cast<const float4*>(s_t_hat + b * NN);
    const float4* wp = reinterpret_cast<const float4*>(W_d + m * NN);
    float acc = 0.f;
    #pragma unroll 8
    for (int i = 0; i < NN / 4; ++i) {
      float4 a = sp[i], w = wp[i];
      acc += a.x * w.x + a.y * w.y + a.z * w.z + a.w * w.w;
    }
    decfea[idx] = acc + b_d[m];
  }
}

// ---------------------------------------------------------------------------
// Score kernel: 2048 blocks x 512 threads (8 waves), 32-row fp32 tile in LDS.
// Stage: 8 x global_load_lds(16B) per thread, LINEAR LDS dest, per-lane
// pre-swizzled global source (granule g' reads source granule g'^(row&7)).
// Reads apply the same XOR -> conflict-spread ds_read_b128 (guide G4 recipe).
// bf16 convert happens in-loop on the VALU pipe (overlaps MFMA pipe).
// Wave w owns m-tiles [w*4,w*4+4) (64 cols); acc = 4q x 2rt x f32x4 = 32 regs.
// ---------------------------------------------------------------------------
__global__ __launch_bounds__(512, 4)
void score_kernel(const float* __restrict__ h,
                  const float* __restrict__ coverage,
                  const float* __restrict__ beta,
                  const float* __restrict__ W_c,
                  const float* __restrict__ v,
                  const uint4* __restrict__ Wpack,
                  const float* __restrict__ decfea,
                  float* __restrict__ weighted) {
  __shared__ __align__(16) float Abuf[RPB * NN];  // 64 KiB fp32 tile (swizzled)
  __shared__ float scorebuf[8][RPB];              // 1 KiB
  int tid  = threadIdx.x;
  int lane = tid & 63;
  int w    = tid >> 6;                  // wave id 0..7
  int lh   = lane >> 4;                 // A-frag k-group
  int lr   = lane & 15;                 // A-frag row
  int col  = lane & 15;                 // C/D col
  int rhi  = (lane >> 4) << 2;          // C/D row base
  int rb   = blockIdx.x;
  int bidx = rb >> 7;                   // 128 blocks per batch

  // ---- async stage: raw fp32 h tile -> LDS, linear dest, swizzled source ----
  const float* hblk = h + (size_t)rb * RPB * NN;
  #pragma unroll
  for (int i = 0; i < 8; ++i) {
    int p       = i * 512 + tid;              // linear dest granule (16B units)
    int row     = p >> 7;                     // 128 granules per row
    int gp      = p & 127;
    int srcg    = row * 128 + (gp ^ (row & 7));
    int destg   = i * 512 + ((tid >> 6) << 6);  // wave-uniform base granule
    __builtin_amdgcn_global_load_lds(
        (const __attribute__((address_space(1))) void*)(hblk + srcg * 4),
        (__attribute__((address_space(3))) void*)(&Abuf[destg * 4]),
        16, 0, 0);
  }

  // ---- hoist epilogue operands (independent of LDS) ----
  float cvl[2][4];
  #pragma unroll
  for (int rt = 0; rt < 2; ++rt)
    #pragma unroll
    for (int r = 0; r < 4; ++r)
      cvl[rt][r] = coverage[rb * RPB + rt * 16 + rhi + r];
  float dv[4], wc[4], vv[4];
  #pragma unroll
  for (int q = 0; q < 4; ++q) {
    int m = (w * 4 + q) * 16 + col;
    dv[q] = decfea[bidx * NN + m];
    wc[q] = W_c[m];
    vv[q] = v[m];
  }

  __syncthreads();                      // drains LDS-DMA (vmcnt 0)

  f32x4 acc[4][2];
  const f32x4 zz = {0.f, 0.f, 0.f, 0.f};
  #pragma unroll
  for (int q = 0; q < 4; ++q)
    #pragma unroll
    for (int rt = 0; rt < 2; ++rt) acc[q][rt] = zz;

  const f32x4*  Af = reinterpret_cast<const f32x4*>(Abuf);
  const bf16x8* Bv = reinterpret_cast<const bf16x8*>(Wpack) + (size_t)(w * 4) * 16 * 64 + lane;

  // row/granule constants for this lane's two row-tiles
  int row0 = lr,      c70 = row0 & 7;
  int row1 = 16 + lr, c71 = row1 & 7;

  // software-prefetched B (depth 1)
  bf16x8 bf[4];
  #pragma unroll
  for (int q = 0; q < 4; ++q)
    bf[q] = Bv[(q * 16 + 0) * 64];
  for (int ks = 0; ks < 16; ++ks) {
    int g = ks * 8 + lh * 2;
    f32x4 lo0 = Af[row0 * 128 + (g ^ c70)];
    f32x4 hi0 = Af[row0 * 128 + ((g + 1) ^ c70)];
    f32x4 lo1 = Af[row1 * 128 + (g ^ c71)];
    f32x4 hi1 = Af[row1 * 128 + ((g + 1) ^ c71)];
    bf16x8 af0 = cvt8(lo0, hi0);
    bf16x8 af1 = cvt8(lo1, hi1);
    bf16x8 bn[4];
    if (ks < 15) {
      #pragma unroll
      for (int q = 0; q < 4; ++q)
        bn[q] = Bv[(q * 16 + ks + 1) * 64];
    }
    #pragma unroll
    for (int q = 0; q < 4; ++q) {
      acc[q][0] = __builtin_amdgcn_mfma_f32_16x16x32_bf16(af0, bf[q], acc[q][0], 0, 0, 0);
      acc[q][1] = __builtin_amdgcn_mfma_f32_16x16x32_bf16(af1, bf[q], acc[q][1], 0, 0, 0);
    }
    if (ks < 15) {
      #pragma unroll
      for (int q = 0; q < 4; ++q) bf[q] = bn[q];
    }
  }

  // ---- epilogue: + dec_fea + cov*W_c, tanh, v-weighted reduce over m ----
  float sc[2][4] = {};
  #pragma unroll
  for (int q = 0; q < 4; ++q)
    #pragma unroll
    for (int rt = 0; rt < 2; ++rt)
      #pragma unroll
      for (int r = 0; r < 4; ++r) {
        float x = acc[q][rt][r] + dv[q] + cvl[rt][r] * wc[q];
        sc[rt][r] += vv[q] * tanh_fast(x);
      }
  #pragma unroll
  for (int rt = 0; rt < 2; ++rt)
    #pragma unroll
    for (int r = 0; r < 4; ++r) {
      float s = sc[rt][r];
      s += __shfl_xor(s, 1);
      s += __shfl_xor(s, 2);
      s += __shfl_xor(s, 4);
      s += __shfl_xor(s, 8);
      sc[rt][r] = s;
    }

  if (col == 0) {
    #pragma unroll
    for (int rt = 0; rt < 2; ++rt)
      #pragma unroll
      for (int r = 0; r < 4; ++r)
        scorebuf[w][rt * 16 + rhi + r] = sc[rt][r];
  }
  __syncthreads();
  if (tid < RPB) {
    float total = 0.f;
    #pragma unroll
    for (int ww = 0; ww < 8; ++ww) total += scorebuf[ww][tid];
    int gl = rb * RPB + tid;
    int lb = gl & (LPB - 1);
    int s  = lb >> 7;                   // TK = 128
    weighted[bidx * LPB + lb] = beta[bidx * SS + s] * total;
  }
}

// ---------------------------------------------------------------------------
// Softmax over 4096 per batch, mask, renormalize; write attn_dist + coverage_new.
// Also zeroes c_t for the following atomic-accumulate kernel.
// ---------------------------------------------------------------------------
__global__ void softmax_kernel(const float* __restrict__ coverage,
                               const float* __restrict__ mask,
                               float* __restrict__ out) {
  int b = blockIdx.x;
  int t = threadIdx.x;
  float* ct   = out;                     // [0, 8192)
  float* attn = out + 8192;              // weighted in, attn_dist out
  float* covn = out + 8192 + 65536;      // coverage_new

  ct[b * NN + t] = 0.f;
  ct[b * NN + 256 + t] = 0.f;

  float wv[16];
  float mx = -1e30f;
  #pragma unroll
  for (int i = 0; i < 16; ++i) {
    wv[i] = attn[b * LPB + i * 256 + t];
    mx = fmaxf(mx, wv[i]);
  }
  __shared__ float redm[4], reds[4];
  mx = fmaxf(mx, __shfl_xor(mx, 1));
  mx = fmaxf(mx, __shfl_xor(mx, 2));
  mx = fmaxf(mx, __shfl_xor(mx, 4));
  mx = fmaxf(mx, __shfl_xor(mx, 8));
  mx = fmaxf(mx, __shfl_xor(mx, 16));
  mx = fmaxf(mx, __shfl_xor(mx, 32));
  if ((t & 63) == 0) redm[t >> 6] = mx;
  __syncthreads();
  mx = fmaxf(fmaxf(redm[0], redm[1]), fmaxf(redm[2], redm[3]));

  float e[16];
  float sum = 0.f;
  #pragma unroll
  for (int i = 0; i < 16; ++i) {
    e[i] = __expf(wv[i] - mx) * mask[b * LPB + i * 256 + t];
    sum += e[i];
  }
  sum += __shfl_xor(sum, 1);
  sum += __shfl_xor(sum, 2);
  sum += __shfl_xor(sum, 4);
  sum += __shfl_xor(sum, 8);
  sum += __shfl_xor(sum, 16);
  sum += __shfl_xor(sum, 32);
  if ((t & 63) == 0) reds[t >> 6] = sum;
  __syncthreads();
  sum = reds[0] + reds[1] + reds[2] + reds[3];
  float inv = 1.0f / sum;
  #pragma unroll
  for (int i = 0; i < 16; ++i) {
    int l = i * 256 + t;
    float a = e[i] * inv;
    attn[b * LPB + l] = a;
    covn[b * LPB + l] = coverage[b * LPB + l] + a;
  }
}

// ---------------------------------------------------------------------------
// c_t[b][n] = sum_l attn[b][l] * h[b][l][n]  (memory-bound, atomic partials)
// R3-proven version: float2 loads, one atomic per distinct address.
// ---------------------------------------------------------------------------
__global__ void ct_kernel(const float* __restrict__ h, float* __restrict__ out) {
  int blk   = blockIdx.x;                // 1024
  int b     = blk >> 6;
  int chunk = blk & 63;
  int t     = threadIdx.x;
  const float* attn = out + 8192 + b * LPB + chunk * 64;
  __shared__ float as_[64];
  if (t < 64) as_[t] = attn[t];
  __syncthreads();
  const float* hp = h + (size_t)(b * LPB + chunk * 64) * NN;
  float a0 = 0.f, a1 = 0.f;
  #pragma unroll 4
  for (int r = 0; r < 64; ++r) {
    float2 hv = *reinterpret_cast<const float2*>(hp + r * NN + t * 2);
    float av = as_[r];
    a0 += av * hv.x;
    a1 += av * hv.y;
  }
  atomicAdd(&out[b * NN + t * 2],     a0);
  atomicAdd(&out[b * NN + t * 2 + 1], a1);
}

extern "C" void kernel_launch(void* const* d_in, const int* in_sizes, int n_in,
                              void* d_out, int out_size, void* d_ws, size_t ws_size,
                              hipStream_t stream) {
  const float* s_t_hat  = (const float*)d_in[0];
  const float* h        = (const float*)d_in[1];
  const float* coverage = (const float*)d_in[2];
  const float* mask     = (const float*)d_in[3];
  const float* beta     = (const float*)d_in[4];
  const float* W_h      = (const float*)d_in[5];
  const float* W_c      = (const float*)d_in[6];
  const float* W_d      = (const float*)d_in[7];
  const float* b_d      = (const float*)d_in[8];
  const float* v        = (const float*)d_in[9];
  float* out = (float*)d_out;

  uint4* Wpack    = (uint4*)d_ws;               // 512 KiB
  float* decfea   = out + 8192 + 65536;         // staged in coverage_new region
  float* weighted = out + 8192;                 // staged in attn_dist region

  prep_kernel <<<80, 512, 0, stream>>>(W_h, Wpack, s_t_hat, W_d, b_d, decfea);
  score_kernel<<<NTILES, 512, 0, stream>>>(h, coverage, beta, W_c, v,
                                           Wpack, decfea, weighted);
  softmax_kernel<<<16, 256, 0, stream>>>(coverage, mask, out);
  ct_kernel<<<1024, 256, 0, stream>>>(h, out);
}